// Round 3
// baseline (456.553 us; speedup 1.0000x reference)
//
#include <hip/hip_runtime.h>

// 5-level 3D Haar wavedec (db1, mode=zero), input [4,8,128,128,128] fp32.
// V3: FULLY FUSED single kernel. A 5-level Haar transform is block-local:
// each Yl voxel depends on exactly a 32^3 input region. Each block owns a
// 128(W)x32(H)x32(D) brick (4 Yl voxels), computes L1 from global (16B/lane
// nontemporal loads), keeps only the aaa chain in LDS (69.6KB + 9.2KB + tiny),
// and cascades L2..L5 with __syncthreads. Details stream out nontemporal.
// Zero workspace traffic: exactly 256MB read + 256MB write (the minimum).
// Grid: 512 blocks x 512 threads = exactly 2 blocks/CU, both LDS-resident.

#define C3 0.3535533905932738f  // (1/sqrt(2))^3

typedef float f4 __attribute__((ext_vector_type(4)));

__device__ __forceinline__ f4 ntload(const float* p) {
    return __builtin_nontemporal_load((const f4*)p);
}
__device__ __forceinline__ void ntstore(float* p, f4 v) {
    __builtin_nontemporal_store(v, (f4*)p);
}

// 4 output voxels along W from rows r[4][8] = {(d0,h0),(d0,h1),(d1,h0),(d1,h1)}
__device__ __forceinline__ void haar_quad(const float r[4][8], float o[8][4]) {
#pragma unroll
    for (int j = 0; j < 4; ++j) {
        const float aw0 = r[0][2*j] + r[0][2*j+1], dw0 = r[0][2*j] - r[0][2*j+1];
        const float aw1 = r[1][2*j] + r[1][2*j+1], dw1 = r[1][2*j] - r[1][2*j+1];
        const float aw2 = r[2][2*j] + r[2][2*j+1], dw2 = r[2][2*j] - r[2][2*j+1];
        const float aw3 = r[3][2*j] + r[3][2*j+1], dw3 = r[3][2*j] - r[3][2*j+1];
        const float aa0 = aw0 + aw1, da0 = aw0 - aw1, ad0 = dw0 + dw1, dd0 = dw0 - dw1;
        const float aa1 = aw2 + aw3, da1 = aw2 - aw3, ad1 = dw2 + dw3, dd1 = dw2 - dw3;
        // subband order matches KEYS (letters = D,H,W): aaa,aad,ada,add,daa,dad,dda,ddd
        o[0][j] = (aa0 + aa1) * C3;
        o[1][j] = (ad0 + ad1) * C3;
        o[2][j] = (da0 + da1) * C3;
        o[3][j] = (dd0 + dd1) * C3;
        o[4][j] = (aa0 - aa1) * C3;
        o[5][j] = (ad0 - ad1) * C3;
        o[6][j] = (da0 - da1) * C3;
        o[7][j] = (dd0 - dd1) * C3;
    }
}

__device__ __forceinline__ void lds_quad(const float* p, int dh, int dd, float r[4][8]) {
    *(f4*)&r[0][0] = *(const f4*)(p);
    *(f4*)&r[0][4] = *(const f4*)(p + 4);
    *(f4*)&r[1][0] = *(const f4*)(p + dh);
    *(f4*)&r[1][4] = *(const f4*)(p + dh + 4);
    *(f4*)&r[2][0] = *(const f4*)(p + dd);
    *(f4*)&r[2][4] = *(const f4*)(p + dd + 4);
    *(f4*)&r[3][0] = *(const f4*)(p + dd + dh);
    *(f4*)&r[3][4] = *(const f4*)(p + dd + dh + 4);
}

__global__ __launch_bounds__(512, 4) void haar3_fused(
    const float* __restrict__ in, float* __restrict__ out)
{
    // aaa-chain staging; W-strides padded (68, 36) to spread LDS banks.
    __shared__ float A1[16 * 16 * 68];  // L1 aaa: 64(W) x16(H) x16(D), 69632 B
    __shared__ float A2[8 * 8 * 36];    // L2 aaa: 32x8x8, 9216 B
    __shared__ float A3[4 * 4 * 16];    // L3 aaa: 16x4x4, 1024 B
    __shared__ float A4[2 * 2 * 8];     // L4 aaa: 8x2x2, 128 B  (total 78.1 KiB)

    const int tid = threadIdx.x;
    const int bc = blockIdx.x >> 4;          // batch*channel in [0,32)
    const int db = (blockIdx.x >> 2) & 3;    // D brick
    const int hb = blockIdx.x & 3;           // H brick

    const float* xin = in + (((long)bc * 128 + db * 32) * 128 + hb * 32) * 128;
    float* const d1 = out + 8388608;   // L1 details, subband size 8388608
    float* const d2 = out + 1048576;   // L2, 1048576
    float* const d3 = out + 131072;    // L3, 131072
    float* const d4 = out + 16384;     // L4, 16384
    float* const d5 = out + 2048;      // L5, 2048; Yl at out+0

    // ---- L1: global 128x32x32 brick -> 64x16x16 per subband (4096 quads) ----
    for (int it = 0; it < 8; ++it) {
        const int u = it * 512 + tid;
        const int wg = u & 15, hy = (u >> 4) & 15, dz = u >> 8;
        const float* p = xin + ((long)(2 * dz) * 128 + 2 * hy) * 128 + 8 * wg;
        float r[4][8];
        *(f4*)&r[0][0] = ntload(p);
        *(f4*)&r[0][4] = ntload(p + 4);
        *(f4*)&r[1][0] = ntload(p + 128);
        *(f4*)&r[1][4] = ntload(p + 132);
        *(f4*)&r[2][0] = ntload(p + 16384);
        *(f4*)&r[2][4] = ntload(p + 16388);
        *(f4*)&r[3][0] = ntload(p + 16512);
        *(f4*)&r[3][4] = ntload(p + 16516);
        float o[8][4];
        haar_quad(r, o);
        *(f4*)&A1[(dz * 16 + hy) * 68 + 4 * wg] = *(const f4*)&o[0][0];
        const long di = (((long)bc * 64 + db * 16 + dz) * 64 + hb * 16 + hy) * 64 + 4 * wg;
#pragma unroll
        for (int s = 0; s < 7; ++s)
            ntstore(d1 + (long)s * 8388608 + di, *(const f4*)&o[s + 1][0]);
    }
    __syncthreads();

    // ---- L2: A1 64x16x16 -> 32x8x8 (512 quads, all threads) ----
    {
        const int wg = tid & 7, hy = (tid >> 3) & 7, dz = tid >> 6;
        float r[4][8];
        lds_quad(&A1[((2 * dz) * 16 + 2 * hy) * 68 + 8 * wg], 68, 16 * 68, r);
        float o[8][4];
        haar_quad(r, o);
        *(f4*)&A2[(dz * 8 + hy) * 36 + 4 * wg] = *(const f4*)&o[0][0];
        const long di = (((long)bc * 32 + db * 8 + dz) * 32 + hb * 8 + hy) * 32 + 4 * wg;
#pragma unroll
        for (int s = 0; s < 7; ++s)
            ntstore(d2 + (long)s * 1048576 + di, *(const f4*)&o[s + 1][0]);
    }
    __syncthreads();

    // ---- L3: A2 32x8x8 -> 16x4x4 (64 quads) ----
    if (tid < 64) {
        const int wg = tid & 3, hy = (tid >> 2) & 3, dz = tid >> 4;
        float r[4][8];
        lds_quad(&A2[((2 * dz) * 8 + 2 * hy) * 36 + 8 * wg], 36, 8 * 36, r);
        float o[8][4];
        haar_quad(r, o);
        *(f4*)&A3[(dz * 4 + hy) * 16 + 4 * wg] = *(const f4*)&o[0][0];
        const long di = (((long)bc * 16 + db * 4 + dz) * 16 + hb * 4 + hy) * 16 + 4 * wg;
#pragma unroll
        for (int s = 0; s < 7; ++s)
            ntstore(d3 + (long)s * 131072 + di, *(const f4*)&o[s + 1][0]);
    }
    __syncthreads();

    // ---- L4: A3 16x4x4 -> 8x2x2 (8 quads) ----
    if (tid < 8) {
        const int wg = tid & 1, hy = (tid >> 1) & 1, dz = tid >> 2;
        float r[4][8];
        lds_quad(&A3[((2 * dz) * 4 + 2 * hy) * 16 + 8 * wg], 16, 64, r);
        float o[8][4];
        haar_quad(r, o);
        *(f4*)&A4[(dz * 2 + hy) * 8 + 4 * wg] = *(const f4*)&o[0][0];
        const long di = (((long)bc * 8 + db * 2 + dz) * 8 + hb * 2 + hy) * 8 + 4 * wg;
#pragma unroll
        for (int s = 0; s < 7; ++s)
            ntstore(d4 + (long)s * 16384 + di, *(const f4*)&o[s + 1][0]);
    }
    __syncthreads();

    // ---- L5: A4 8x2x2 -> 4x1x1 (1 quad) ----
    if (tid == 0) {
        float r[4][8];
        lds_quad(&A4[0], 8, 16, r);
        float o[8][4];
        haar_quad(r, o);
        const long di = (((long)bc * 4 + db) * 4 + hb) * 4;
        *(f4*)(out + di) = *(const f4*)&o[0][0];  // Yl
#pragma unroll
        for (int s = 0; s < 7; ++s)
            *(f4*)(d5 + (long)s * 2048 + di) = *(const f4*)&o[s + 1][0];
    }
}

extern "C" void kernel_launch(void* const* d_in, const int* in_sizes, int n_in,
                              void* d_out, int out_size, void* d_ws, size_t ws_size,
                              hipStream_t stream) {
    const float* x = (const float*)d_in[0];
    float* out = (float*)d_out;
    (void)d_ws; (void)ws_size;  // no workspace needed — fully fused

    // d_out layout (flat, fp32): Yl[2048] | L5 det 7x2048 | L4 det 7x16384 |
    // L3 det 7x131072 | L2 det 7x1048576 | L1 det 7x8388608
    haar3_fused<<<512, 512, 0, stream>>>(x, out);
}

// Round 4
// 452.252 us; speedup vs baseline: 1.0095x; 1.0095x over previous
//
#include <hip/hip_runtime.h>

// 5-level 3D Haar wavedec (db1, mode=zero), input [4,8,128,128,128] fp32.
// V4: fused single kernel, occupancy-tuned. Brick = 64(W)x32(H)x32(D)
// (two complete 32^3 Yl regions) -> LDS 36 KiB/block (A3,A4 alias A1,A2),
// 1024 blocks x 512 threads, up to 4 blocks/CU (vs V3's 2 at 78 KiB).
// A1 is stored with a 4-float-chunk XOR swizzle keyed on (dz>>1)^(hy>>1)
// (L2 reads even rows, so the usual row&7 key degenerates) to kill the
// 16-way ds_read conflict unpadded stride-32 would cause.
// Traffic: exactly 256 MB read + 256 MB write (minimum).

#define C3 0.3535533905932738f  // (1/sqrt(2))^3

typedef float f4 __attribute__((ext_vector_type(4)));
typedef float f2 __attribute__((ext_vector_type(2)));

__device__ __forceinline__ f4 ntload(const float* p) {
    return __builtin_nontemporal_load((const f4*)p);
}
__device__ __forceinline__ void ntstore(float* p, f4 v) {
    __builtin_nontemporal_store(v, (f4*)p);
}

// 4 output voxels along W from rows r[4][8] = {(d0,h0),(d0,h1),(d1,h0),(d1,h1)}
__device__ __forceinline__ void haar_quad(const float r[4][8], float o[8][4]) {
#pragma unroll
    for (int j = 0; j < 4; ++j) {
        const float aw0 = r[0][2*j] + r[0][2*j+1], dw0 = r[0][2*j] - r[0][2*j+1];
        const float aw1 = r[1][2*j] + r[1][2*j+1], dw1 = r[1][2*j] - r[1][2*j+1];
        const float aw2 = r[2][2*j] + r[2][2*j+1], dw2 = r[2][2*j] - r[2][2*j+1];
        const float aw3 = r[3][2*j] + r[3][2*j+1], dw3 = r[3][2*j] - r[3][2*j+1];
        const float aa0 = aw0 + aw1, da0 = aw0 - aw1, ad0 = dw0 + dw1, dd0 = dw0 - dw1;
        const float aa1 = aw2 + aw3, da1 = aw2 - aw3, ad1 = dw2 + dw3, dd1 = dw2 - dw3;
        // subband order matches KEYS (letters = D,H,W): aaa,aad,ada,add,daa,dad,dda,ddd
        o[0][j] = (aa0 + aa1) * C3;
        o[1][j] = (ad0 + ad1) * C3;
        o[2][j] = (da0 + da1) * C3;
        o[3][j] = (dd0 + dd1) * C3;
        o[4][j] = (aa0 - aa1) * C3;
        o[5][j] = (ad0 - ad1) * C3;
        o[6][j] = (da0 - da1) * C3;
        o[7][j] = (dd0 - dd1) * C3;
    }
}

// Swizzled float index into A1 for logical [dz][hy][c4 .. c4+4), dz,hy in [0,16),
// c4 a 4-aligned W offset in [0,32). XOR key uses bit1+ of dz,hy so that the
// even-row reads at L2 (rows 2dz2+a, 2hy2+b) still get a spreading key.
__device__ __forceinline__ int sw1(int dz, int hy, int c4) {
    return (dz * 16 + hy) * 32 + (c4 ^ ((((dz >> 1) ^ (hy >> 1)) & 7) << 2));
}

__global__ __launch_bounds__(512, 4) void haar3_fused(
    const float* __restrict__ in, float* __restrict__ out)
{
    __shared__ float A1[16 * 16 * 32];  // L1 aaa: 32(W)x16x16, swizzled, 32 KiB
    __shared__ float A2[8 * 8 * 16];    // L2 aaa: 16x8x8, 4 KiB
    float* const A3 = A1;               // L3 aaa: 8x4x4  (A1 dead after L2; stride 8)
    float* const A4 = A2;               // L4 aaa: 4x2x2  (A2 dead after L3; stride 4)

    const int tid = threadIdx.x;
    const int bid = blockIdx.x;
    const int wb = bid & 1, hb = (bid >> 1) & 3, db = (bid >> 3) & 3, bc = bid >> 5;

    const float* xin = in + (((long)bc * 128 + db * 32) * 128 + hb * 32) * 128 + wb * 64;
    float* const d1 = out + 8388608;   // L1 details, subband size 8388608
    float* const d2 = out + 1048576;   // L2, 1048576
    float* const d3 = out + 131072;    // L3, 131072
    float* const d4 = out + 16384;     // L4, 16384
    float* const d5 = out + 2048;      // L5, 2048; Yl at out+0

    // ---- L1: global 64x32x32 brick -> 32x16x16 per subband (2048 quads) ----
#pragma unroll 2
    for (int it = 0; it < 4; ++it) {
        const int u = it * 512 + tid;
        const int wg = u & 7, hy = (u >> 3) & 15, dz = u >> 7;
        const float* p = xin + ((long)(2 * dz) * 128 + 2 * hy) * 128 + 8 * wg;
        float r[4][8];
        *(f4*)&r[0][0] = ntload(p);         *(f4*)&r[0][4] = ntload(p + 4);
        *(f4*)&r[1][0] = ntload(p + 128);   *(f4*)&r[1][4] = ntload(p + 132);
        *(f4*)&r[2][0] = ntload(p + 16384); *(f4*)&r[2][4] = ntload(p + 16388);
        *(f4*)&r[3][0] = ntload(p + 16512); *(f4*)&r[3][4] = ntload(p + 16516);
        float o[8][4];
        haar_quad(r, o);
        *(f4*)&A1[sw1(dz, hy, 4 * wg)] = *(const f4*)&o[0][0];
        const long di = (((long)bc * 64 + db * 16 + dz) * 64 + hb * 16 + hy) * 64
                        + 32 * wb + 4 * wg;
#pragma unroll
        for (int s = 0; s < 7; ++s)
            ntstore(d1 + (long)s * 8388608 + di, *(const f4*)&o[s + 1][0]);
    }
    __syncthreads();

    // ---- L2: A1 32x16x16 -> 16x8x8 (256 quads) ----
    if (tid < 256) {
        const int wg = tid & 3, hy = (tid >> 2) & 7, dz = tid >> 5;
        float r[4][8];
#pragma unroll
        for (int a = 0; a < 2; ++a)
#pragma unroll
            for (int b = 0; b < 2; ++b) {
                *(f4*)&r[a * 2 + b][0] = *(const f4*)&A1[sw1(2*dz + a, 2*hy + b, 8*wg)];
                *(f4*)&r[a * 2 + b][4] = *(const f4*)&A1[sw1(2*dz + a, 2*hy + b, 8*wg + 4)];
            }
        float o[8][4];
        haar_quad(r, o);
        *(f4*)&A2[(dz * 8 + hy) * 16 + 4 * wg] = *(const f4*)&o[0][0];
        const long di = (((long)bc * 32 + db * 8 + dz) * 32 + hb * 8 + hy) * 32
                        + 16 * wb + 4 * wg;
#pragma unroll
        for (int s = 0; s < 7; ++s)
            ntstore(d2 + (long)s * 1048576 + di, *(const f4*)&o[s + 1][0]);
    }
    __syncthreads();

    // ---- L3: A2 16x8x8 -> 8x4x4 (32 quads) ----
    if (tid < 32) {
        const int wg = tid & 1, hy = (tid >> 1) & 3, dz = tid >> 3;
        float r[4][8];
#pragma unroll
        for (int a = 0; a < 2; ++a)
#pragma unroll
            for (int b = 0; b < 2; ++b) {
                const int row = (2 * dz + a) * 8 + 2 * hy + b;
                *(f4*)&r[a * 2 + b][0] = *(const f4*)&A2[row * 16 + 8 * wg];
                *(f4*)&r[a * 2 + b][4] = *(const f4*)&A2[row * 16 + 8 * wg + 4];
            }
        float o[8][4];
        haar_quad(r, o);
        *(f4*)&A3[(dz * 4 + hy) * 8 + 4 * wg] = *(const f4*)&o[0][0];
        const long di = (((long)bc * 16 + db * 4 + dz) * 16 + hb * 4 + hy) * 16
                        + 8 * wb + 4 * wg;
#pragma unroll
        for (int s = 0; s < 7; ++s)
            ntstore(d3 + (long)s * 131072 + di, *(const f4*)&o[s + 1][0]);
    }
    __syncthreads();

    // ---- L4: A3 8x4x4 -> 4x2x2 (4 quads) ----
    if (tid < 4) {
        const int hy = tid & 1, dz = tid >> 1;
        float r[4][8];
#pragma unroll
        for (int a = 0; a < 2; ++a)
#pragma unroll
            for (int b = 0; b < 2; ++b) {
                const int row = (2 * dz + a) * 4 + 2 * hy + b;
                *(f4*)&r[a * 2 + b][0] = *(const f4*)&A3[row * 8];
                *(f4*)&r[a * 2 + b][4] = *(const f4*)&A3[row * 8 + 4];
            }
        float o[8][4];
        haar_quad(r, o);
        *(f4*)&A4[(dz * 2 + hy) * 4] = *(const f4*)&o[0][0];
        const long di = (((long)bc * 8 + db * 2 + dz) * 8 + hb * 2 + hy) * 8 + 4 * wb;
#pragma unroll
        for (int s = 0; s < 7; ++s)
            ntstore(d4 + (long)s * 16384 + di, *(const f4*)&o[s + 1][0]);
    }
    __syncthreads();

    // ---- L5: A4 4x2x2 -> 2x1x1 (one pair) ----
    if (tid == 0) {
        float r[4][4];
#pragma unroll
        for (int k = 0; k < 4; ++k)
            *(f4*)&r[k][0] = *(const f4*)&A4[k * 4];  // rows (dz=a, hy=b) = k
        float o[8][2];
#pragma unroll
        for (int j = 0; j < 2; ++j) {
            const float aw0 = r[0][2*j] + r[0][2*j+1], dw0 = r[0][2*j] - r[0][2*j+1];
            const float aw1 = r[1][2*j] + r[1][2*j+1], dw1 = r[1][2*j] - r[1][2*j+1];
            const float aw2 = r[2][2*j] + r[2][2*j+1], dw2 = r[2][2*j] - r[2][2*j+1];
            const float aw3 = r[3][2*j] + r[3][2*j+1], dw3 = r[3][2*j] - r[3][2*j+1];
            const float aa0 = aw0 + aw1, da0 = aw0 - aw1, ad0 = dw0 + dw1, dd0 = dw0 - dw1;
            const float aa1 = aw2 + aw3, da1 = aw2 - aw3, ad1 = dw2 + dw3, dd1 = dw2 - dw3;
            o[0][j] = (aa0 + aa1) * C3;
            o[1][j] = (ad0 + ad1) * C3;
            o[2][j] = (da0 + da1) * C3;
            o[3][j] = (dd0 + dd1) * C3;
            o[4][j] = (aa0 - aa1) * C3;
            o[5][j] = (ad0 - ad1) * C3;
            o[6][j] = (da0 - da1) * C3;
            o[7][j] = (dd0 - dd1) * C3;
        }
        const long di = (((long)bc * 4 + db) * 4 + hb) * 4 + 2 * wb;
        *(f2*)(out + di) = *(const f2*)&o[0][0];  // Yl
#pragma unroll
        for (int s = 0; s < 7; ++s)
            *(f2*)(d5 + (long)s * 2048 + di) = *(const f2*)&o[s + 1][0];
    }
}

extern "C" void kernel_launch(void* const* d_in, const int* in_sizes, int n_in,
                              void* d_out, int out_size, void* d_ws, size_t ws_size,
                              hipStream_t stream) {
    const float* x = (const float*)d_in[0];
    float* out = (float*)d_out;
    (void)d_ws; (void)ws_size;  // fully fused — no workspace

    // d_out layout (flat, fp32): Yl[2048] | L5 det 7x2048 | L4 det 7x16384 |
    // L3 det 7x131072 | L2 det 7x1048576 | L1 det 7x8388608
    haar3_fused<<<1024, 512, 0, stream>>>(x, out);
}